// Round 4
// baseline (493.985 us; speedup 1.0000x reference)
//
#include <hip/hip_runtime.h>
#include <stdint.h>

typedef unsigned short u16;
typedef __attribute__((ext_vector_type(8))) __bf16 bf16x8;
typedef __attribute__((ext_vector_type(4))) float f32x4;

__device__ __forceinline__ u16 f2bf(float f) {
  union { float f; uint32_t u; } v; v.f = f;
  uint32_t u = v.u;
  uint32_t r = (u + 0x7fffu + ((u >> 16) & 1u)) >> 16;  // RNE
  return (u16)r;
}
__device__ __forceinline__ float bf2f(u16 h) {
  union { uint32_t u; float f; } v; v.u = ((uint32_t)h) << 16;
  return v.f;
}

// async 16B/lane global->LDS. LDS dest = wave-uniform base + lane*16 (m104).
__device__ __forceinline__ void gld16(const void* g, void* l) {
  __builtin_amdgcn_global_load_lds(
      (__attribute__((address_space(1))) void*)(uintptr_t)g,
      (__attribute__((address_space(3))) void*)l,
      16, 0, 0);
}

// ---------------- fused fp32 -> bf16 cast of all 5 inputs ----------------
__global__ __launch_bounds__(256) void cast_all(const float* __restrict__ x,
                                                const float* __restrict__ wq,
                                                const float* __restrict__ wk,
                                                const float* __restrict__ wv,
                                                const float* __restrict__ wo,
                                                u16* __restrict__ xb,
                                                u16* __restrict__ wqkv,
                                                u16* __restrict__ wob) {
  int i = blockIdx.x * 256 + threadIdx.x;
  const float* src; u16* dst; int loc, base;
  if (i < 2097152)      { src = x;  dst = xb;   loc = i;           base = 0; }
  else if (i < 3145728) { src = wq; dst = wqkv; loc = i - 2097152; base = 0; }
  else if (i < 3407872) { src = wk; dst = wqkv; loc = i - 3145728; base = 1048576; }
  else if (i < 3670016) { src = wv; dst = wqkv; loc = i - 3407872; base = 1310720; }
  else                  { src = wo; dst = wob;  loc = i - 3670016; base = 0; }
  float4 f = ((const float4*)src)[loc];
  ushort4 o;
  o.x = f2bf(f.x); o.y = f2bf(f.y); o.z = f2bf(f.z); o.w = f2bf(f.w);
  ((ushort4*)dst)[base + loc] = o;
}

// ---------------- bf16 GEMM, C = A * B^T  (m97-style staging) ----------------
__global__ __launch_bounds__(256) void gemm_bt(const u16* __restrict__ A,
                                               const u16* __restrict__ B,
                                               void* __restrict__ C,
                                               int M, int N, int K, int out_f32)
{
  __shared__ u16 As[128 * 32];
  __shared__ u16 Bs[128 * 32];
  const int tid  = threadIdx.x;
  const int wave = tid >> 6, lane = tid & 63;
  const int col  = lane & 15, quad = lane >> 4;
  const int bm = blockIdx.y, bn = blockIdx.x;
  const int wm = (wave >> 1) * 64, wn = (wave & 1) * 64;
  const size_t arow0 = (size_t)bm * 128, brow0 = (size_t)bn * 128;

  const int srow = wave * 32 + (lane >> 2);
  const int soff = (((lane & 3) ^ ((lane >> 2) & 3)) * 8);
  const u16* Ag = A + (arow0 + srow) * K + soff;
  const u16* Bg = B + (brow0 + srow) * K + soff;
  u16* Asw = As + wave * 32 * 32;
  u16* Bsw = Bs + wave * 32 * 32;
  const int swz = (quad ^ (col & 3)) * 8;

  const f32x4 fz = {0.f, 0.f, 0.f, 0.f};
  f32x4 acc[4][4];
  for (int i = 0; i < 4; ++i)
    for (int j = 0; j < 4; ++j) acc[i][j] = fz;

  for (int k0 = 0; k0 < K; k0 += 32) {
    __syncthreads();
    gld16(Ag + k0,                  Asw);
    gld16(Ag + k0 + (size_t)16 * K, Asw + 16 * 32);
    gld16(Bg + k0,                  Bsw);
    gld16(Bg + k0 + (size_t)16 * K, Bsw + 16 * 32);
    __syncthreads();
    bf16x8 af[4];
    #pragma unroll
    for (int mt = 0; mt < 4; ++mt)
      af[mt] = *(const bf16x8*)&As[(wm + mt * 16 + col) * 32 + swz];
    #pragma unroll
    for (int nt = 0; nt < 4; ++nt) {
      bf16x8 bf = *(const bf16x8*)&Bs[(wn + nt * 16 + col) * 32 + swz];
      #pragma unroll
      for (int mt = 0; mt < 4; ++mt)
        acc[mt][nt] = __builtin_amdgcn_mfma_f32_16x16x32_bf16(af[mt], bf, acc[mt][nt], 0, 0, 0);
    }
  }

  #pragma unroll
  for (int mt = 0; mt < 4; ++mt)
    #pragma unroll
    for (int nt = 0; nt < 4; ++nt)
      #pragma unroll
      for (int i = 0; i < 4; ++i) {
        size_t grow = arow0 + wm + mt * 16 + quad * 4 + i;
        size_t gcol = brow0 + wn + nt * 16 + col;
        float v = acc[mt][nt][i];
        if (out_f32) ((float*)C)[grow * N + gcol] = v;
        else         ((u16*)C)[grow * N + gcol]   = f2bf(v);
      }
}

// ---------------- RoPE over fused qkv buffer (row stride 3072) ----------------
__global__ __launch_bounds__(256) void rope_kernel(u16* __restrict__ t, int S, float qscale) {
  int idx = blockIdx.x * 256 + threadIdx.x;   // total = B*S*20*64
  int i = idx & 63;
  int r = idx >> 6;
  int hh = r % 20; r /= 20;
  int s = r % S;
  int b = r / S;
  // inv = 10000^(-2i/128) = exp2(-i * log2(10000)/64)
  float inv = exp2f(-(float)i * 0.20762050593046f);
  float ang = (float)s * inv;
  float sn, cs;
  __sincosf(ang, &sn, &cs);
  int colb = (hh < 16) ? hh * 128 : 2048 + (hh - 16) * 128;
  float osc = (hh < 16) ? qscale : 1.0f;
  size_t base = (size_t)(b * S + s) * 3072 + colb + 2 * i;
  float t0 = bf2f(t[base]), t1 = bf2f(t[base + 1]);
  t[base]     = f2bf((t0 * cs - t1 * sn) * osc);
  t[base + 1] = f2bf((t0 * sn + t1 * cs) * osc);
}

// ---------------- V transpose: qkv[:,2560+kvh*128+d] -> Vtg[(b*4+kvh)*128+d][s] ----
__global__ __launch_bounds__(256) void vtrans_kernel(const u16* __restrict__ qkv,
                                                     u16* __restrict__ Vtg, int S) {
  __shared__ u16 T[64 * 65];
  const int s0 = blockIdx.x * 64, d0 = blockIdx.y * 64, bk = blockIdx.z;
  const int b = bk >> 2, kvh = bk & 3;
  const u16* src = qkv + (size_t)b * S * 3072 + 2560 + kvh * 128 + d0;
  #pragma unroll 4
  for (int it = 0; it < 16; ++it) {
    int idx = it * 256 + threadIdx.x;
    int r = idx >> 6, c = idx & 63;
    T[c * 65 + r] = src[(size_t)(s0 + r) * 3072 + c];
  }
  __syncthreads();
  #pragma unroll 4
  for (int it = 0; it < 16; ++it) {
    int idx = it * 256 + threadIdx.x;
    int d = idx >> 6, s = idx & 63;
    Vtg[((size_t)bk * 128 + d0 + d) * S + s0 + s] = T[d * 65 + s];
  }
}

// ---------------- causal flash attention, GQA 4:1, no-max softmax ----------------
// Barrier-free: K and V fragments read directly from global (L1/L2-resident).
// Grid 512, heavy-qt first; slots g and g+256 sum to constant work.
__global__ __launch_bounds__(256) void attn_kernel(const u16* __restrict__ QKV,
                                                   const u16* __restrict__ Vtg,
                                                   u16* __restrict__ Ctx,
                                                   int B, int S)
{
  const int g = blockIdx.x;
  const int slot = g >> 8, r = g & 255;
  const int qtidx = r >> 5, bh = r & 31;
  const int h = bh & 15, b = bh >> 4;
  const int qt = slot ? qtidx : 15 - qtidx;

  const int tid  = threadIdx.x;
  const int wave = tid >> 6, lane = tid & 63;
  const int col  = lane & 15, quad = lane >> 4;
  const int q0   = qt * 128;
  const int kvh  = h >> 2;

  __shared__ u16 Ps[4][16 * 68];   // per-wave P tile (one mt at a time)

  // Q fragments (scale log2e/sqrt(128) pre-folded in rope)
  bf16x8 aq[2][4];
  #pragma unroll
  for (int mt = 0; mt < 2; ++mt)
    #pragma unroll
    for (int ks = 0; ks < 4; ++ks)
      aq[mt][ks] = *(const bf16x8*)(QKV + (size_t)(b * S + q0 + wave * 32 + mt * 16 + col) * 3072
                                        + h * 128 + ks * 32 + quad * 8);

  const u16* KVb = QKV + (size_t)b * S * 3072 + 2048 + kvh * 128;  // K block
  const u16* Vtb = Vtg + ((size_t)(b * 4 + kvh) * 128) * S;

  const f32x4 fz = {0.f, 0.f, 0.f, 0.f};
  f32x4 o[2][8];
  #pragma unroll
  for (int mt = 0; mt < 2; ++mt)
    #pragma unroll
    for (int nc = 0; nc < 8; ++nc) o[mt][nc] = fz;
  float rs[2][4];
  #pragma unroll
  for (int mt = 0; mt < 2; ++mt)
    #pragma unroll
    for (int i = 0; i < 4; ++i) rs[mt][i] = 0.f;

  const int kt_max = 2 * qt + 1;
  u16* Pw = Ps[wave];

  for (int kt = 0; kt <= kt_max; ++kt) {
    #pragma unroll
    for (int mt = 0; mt < 2; ++mt) {
      const int row0 = q0 + wave * 32 + mt * 16;
      if (kt * 64 > row0 + 15) continue;   // fully masked mtile (wave-uniform)

      // S = Q K^T (16x64): K B-frags straight from global (16B contiguous in d)
      f32x4 sc[4];
      #pragma unroll
      for (int nt = 0; nt < 4; ++nt) {
        const u16* kr = KVb + (size_t)(kt * 64 + nt * 16 + col) * 3072 + quad * 8;
        f32x4 a = fz;
        #pragma unroll
        for (int ks = 0; ks < 4; ++ks) {
          bf16x8 bk = *(const bf16x8*)(kr + ks * 32);
          a = __builtin_amdgcn_mfma_f32_16x16x32_bf16(aq[mt][ks], bk, a, 0, 0, 0);
        }
        sc[nt] = a;
      }

      const bool need_mask = (kt * 64 + 63 > row0);
      float p[4][4];
      #pragma unroll
      for (int nt = 0; nt < 4; ++nt) {
        int kg = kt * 64 + nt * 16 + col;
        #pragma unroll
        for (int i = 0; i < 4; ++i) {
          float s = sc[nt][i];
          if (need_mask && kg > row0 + quad * 4 + i) s = -__builtin_inff();
          float e = exp2f(s);
          p[nt][i] = e;
          rs[mt][i] += e;
        }
      }

      // P: C-layout -> per-wave LDS -> A-layout (same-wave DS is in-order)
      #pragma unroll
      for (int nt = 0; nt < 4; ++nt)
        #pragma unroll
        for (int i = 0; i < 4; ++i)
          Pw[(quad * 4 + i) * 68 + nt * 16 + col] =
              (u16)(__float_as_uint(p[nt][i]) >> 16);
      __asm__ volatile("" ::: "memory");
      bf16x8 ap[2];
      #pragma unroll
      for (int ks = 0; ks < 2; ++ks)
        ap[ks] = *(const bf16x8*)&Pw[col * 68 + ks * 32 + quad * 8];

      // O += P V : V^T B-frags straight from global Vtg (16B contiguous in s)
      #pragma unroll
      for (int nc = 0; nc < 8; ++nc) {
        const u16* vr = Vtb + (size_t)(nc * 16 + col) * S + kt * 64 + quad * 8;
        #pragma unroll
        for (int ks = 0; ks < 2; ++ks) {
          bf16x8 bv = *(const bf16x8*)(vr + ks * 32);
          o[mt][nc] = __builtin_amdgcn_mfma_f32_16x16x32_bf16(ap[ks], bv, o[mt][nc], 0, 0, 0);
        }
      }
    }
  }

  // deferred row-sum: reduce rs across the 16 col-lanes, then normalize
  #pragma unroll
  for (int mt = 0; mt < 2; ++mt) {
    float linv[4];
    #pragma unroll
    for (int i = 0; i < 4; ++i) {
      float v = rs[mt][i];
      #pragma unroll
      for (int off = 1; off < 16; off <<= 1)
        v += __shfl_xor(v, off);
      linv[i] = 1.0f / v;
    }
    #pragma unroll
    for (int nc = 0; nc < 8; ++nc)
      #pragma unroll
      for (int i = 0; i < 4; ++i) {
        int qg = q0 + wave * 32 + mt * 16 + quad * 4 + i;
        Ctx[(size_t)(b * S + qg) * 2048 + h * 128 + nc * 16 + col] =
            f2bf(o[mt][nc][i] * linv[i]);
      }
  }
}

extern "C" void kernel_launch(void* const* d_in, const int* in_sizes, int n_in,
                              void* d_out, int out_size, void* d_ws, size_t ws_size,
                              hipStream_t stream) {
  const int B = 2, S = 2048, D = 2048;
  const int M = B * S;            // 4096
  const int NQKV = 3072;          // q 0..2047 | k 2048..2559 | v 2560..3071

  const float* x  = (const float*)d_in[0];
  const float* wq = (const float*)d_in[1];
  const float* wk = (const float*)d_in[2];
  const float* wv = (const float*)d_in[3];
  const float* wo = (const float*)d_in[4];

  char* ws = (char*)d_ws;
  u16* xb    = (u16*)ws; ws += (size_t)M * D * 2;
  u16* wqkvb = (u16*)ws; ws += (size_t)NQKV * D * 2;
  u16* wob   = (u16*)ws; ws += (size_t)D * D * 2;
  u16* qkvb  = (u16*)ws; ws += (size_t)M * NQKV * 2;
  u16* vtg   = (u16*)ws; ws += (size_t)B * 4 * 128 * S * 2;
  u16* ctx   = (u16*)ws; ws += (size_t)M * D * 2;

  cast_all<<<18432, 256, 0, stream>>>(x, wq, wk, wv, wo, xb, wqkvb, wob);

  gemm_bt<<<dim3(NQKV / 128, M / 128), 256, 0, stream>>>(xb, wqkvb, qkvb, M, NQKV, D, 0);

  // qscale = log2(e)/sqrt(128), folded so attention uses exp2 directly
  const float qscale = 0.12751744515623627f;
  rope_kernel<<<(M * 20 * 64) / 256, 256, 0, stream>>>(qkvb, S, qscale);

  vtrans_kernel<<<dim3(S / 64, 2, B * 4), 256, 0, stream>>>(qkvb, vtg, S);

  attn_kernel<<<512, 256, 0, stream>>>(qkvb, vtg, ctx, B, S);

  gemm_bt<<<dim3(D / 128, M / 128), 256, 0, stream>>>(ctx, wob, d_out, M, D, D, 1);
}

// Round 5
// 450.558 us; speedup vs baseline: 1.0964x; 1.0964x over previous
//
#include <hip/hip_runtime.h>
#include <stdint.h>

typedef unsigned short u16;
typedef __attribute__((ext_vector_type(8))) __bf16 bf16x8;
typedef __attribute__((ext_vector_type(4))) float f32x4;

__device__ __forceinline__ u16 f2bf(float f) {
  union { float f; uint32_t u; } v; v.f = f;
  uint32_t u = v.u;
  uint32_t r = (u + 0x7fffu + ((u >> 16) & 1u)) >> 16;  // RNE
  return (u16)r;
}
__device__ __forceinline__ float bf2f(u16 h) {
  union { uint32_t u; float f; } v; v.u = ((uint32_t)h) << 16;
  return v.f;
}

// async 16B/lane global->LDS. LDS dest = wave-uniform base + lane*16 (m104).
__device__ __forceinline__ void gld16(const void* g, void* l) {
  __builtin_amdgcn_global_load_lds(
      (__attribute__((address_space(1))) void*)(uintptr_t)g,
      (__attribute__((address_space(3))) void*)l,
      16, 0, 0);
}

// ---------------- fused fp32 -> bf16 cast of all 5 inputs ----------------
__global__ __launch_bounds__(256) void cast_all(const float* __restrict__ x,
                                                const float* __restrict__ wq,
                                                const float* __restrict__ wk,
                                                const float* __restrict__ wv,
                                                const float* __restrict__ wo,
                                                u16* __restrict__ xb,
                                                u16* __restrict__ wqkv,
                                                u16* __restrict__ wob) {
  int i = blockIdx.x * 256 + threadIdx.x;
  const float* src; u16* dst; int loc, base;
  if (i < 2097152)      { src = x;  dst = xb;   loc = i;           base = 0; }
  else if (i < 3145728) { src = wq; dst = wqkv; loc = i - 2097152; base = 0; }
  else if (i < 3407872) { src = wk; dst = wqkv; loc = i - 3145728; base = 1048576; }
  else if (i < 3670016) { src = wv; dst = wqkv; loc = i - 3407872; base = 1310720; }
  else                  { src = wo; dst = wob;  loc = i - 3670016; base = 0; }
  float4 f = ((const float4*)src)[loc];
  ushort4 o;
  o.x = f2bf(f.x); o.y = f2bf(f.y); o.z = f2bf(f.z); o.w = f2bf(f.w);
  ((ushort4*)dst)[base + loc] = o;
}

// ---------------- bf16 GEMM, C = A * B^T  (BK=64, m97-style staging) ----------------
// 128x128 tile, 4 waves 2x2, each 64x64 = 4x4 MFMA 16x16x32. 8-chunk xor swizzle.
__global__ __launch_bounds__(256) void gemm_bt(const u16* __restrict__ A,
                                               const u16* __restrict__ B,
                                               void* __restrict__ C,
                                               int M, int N, int K, int out_f32)
{
  __shared__ u16 As[128 * 64];
  __shared__ u16 Bs[128 * 64];
  const int tid  = threadIdx.x;
  const int wave = tid >> 6, lane = tid & 63;
  const int col  = lane & 15, quad = lane >> 4;
  const int bm = blockIdx.y, bn = blockIdx.x;
  const int wm = (wave >> 1) * 64, wn = (wave & 1) * 64;
  const size_t arow0 = (size_t)bm * 128, brow0 = (size_t)bn * 128;

  const int sr = lane >> 3, pc = lane & 7;   // staging: 8 rows x 8 chunks / issue

  const f32x4 fz = {0.f, 0.f, 0.f, 0.f};
  f32x4 acc[4][4];
  for (int i = 0; i < 4; ++i)
    for (int j = 0; j < 4; ++j) acc[i][j] = fz;

  for (int k0 = 0; k0 < K; k0 += 64) {
    __syncthreads();
    #pragma unroll
    for (int i = 0; i < 4; ++i) {
      int rA = wave * 32 + i * 8 + sr;
      int lc = pc ^ (rA & 7);
      gld16(A + (arow0 + rA) * K + k0 + lc * 8, As + (wave * 32 + i * 8) * 64);
      gld16(B + (brow0 + rA) * K + k0 + lc * 8, Bs + (wave * 32 + i * 8) * 64);
    }
    __syncthreads();
    #pragma unroll
    for (int kk = 0; kk < 2; ++kk) {
      const int swz = (((kk * 4 + quad) ^ (col & 7)) * 8);
      bf16x8 af[4];
      #pragma unroll
      for (int mt = 0; mt < 4; ++mt)
        af[mt] = *(const bf16x8*)&As[(wm + mt * 16 + col) * 64 + swz];
      #pragma unroll
      for (int nt = 0; nt < 4; ++nt) {
        bf16x8 bf = *(const bf16x8*)&Bs[(wn + nt * 16 + col) * 64 + swz];
        #pragma unroll
        for (int mt = 0; mt < 4; ++mt)
          acc[mt][nt] = __builtin_amdgcn_mfma_f32_16x16x32_bf16(af[mt], bf, acc[mt][nt], 0, 0, 0);
      }
    }
  }

  // C/D layout: col=lane&15, row=quad*4+reg (m89)
  #pragma unroll
  for (int mt = 0; mt < 4; ++mt)
    #pragma unroll
    for (int nt = 0; nt < 4; ++nt)
      #pragma unroll
      for (int i = 0; i < 4; ++i) {
        size_t grow = arow0 + wm + mt * 16 + quad * 4 + i;
        size_t gcol = brow0 + wn + nt * 16 + col;
        float v = acc[mt][nt][i];
        if (out_f32) ((float*)C)[grow * N + gcol] = v;
        else         ((u16*)C)[grow * N + gcol]   = f2bf(v);
      }
}

// ---------------- RoPE over fused qkv buffer (row stride 3072) ----------------
__global__ __launch_bounds__(256) void rope_kernel(u16* __restrict__ t, int S, float qscale) {
  int idx = blockIdx.x * 256 + threadIdx.x;   // total = B*S*20*64
  int i = idx & 63;
  int r = idx >> 6;
  int hh = r % 20; r /= 20;
  int s = r % S;
  int b = r / S;
  float inv = exp2f(-(float)i * 0.20762050593046f);  // 10000^(-2i/128)
  float ang = (float)s * inv;
  float sn, cs;
  __sincosf(ang, &sn, &cs);
  int colb = (hh < 16) ? hh * 128 : 2048 + (hh - 16) * 128;
  float osc = (hh < 16) ? qscale : 1.0f;
  size_t base = (size_t)(b * S + s) * 3072 + colb + 2 * i;
  float t0 = bf2f(t[base]), t1 = bf2f(t[base + 1]);
  t[base]     = f2bf((t0 * cs - t1 * sn) * osc);
  t[base + 1] = f2bf((t0 * sn + t1 * cs) * osc);
}

// ---------------- V transpose: qkv[:,2560+kvh*128+d] -> Vtg[(b*4+kvh)*128+d][s] ----
__global__ __launch_bounds__(256) void vtrans_kernel(const u16* __restrict__ qkv,
                                                     u16* __restrict__ Vtg, int S) {
  __shared__ u16 T[64 * 65];
  const int s0 = blockIdx.x * 64, d0 = blockIdx.y * 64, bk = blockIdx.z;
  const int b = bk >> 2, kvh = bk & 3;
  const u16* src = qkv + (size_t)b * S * 3072 + 2560 + kvh * 128 + d0;
  #pragma unroll 4
  for (int it = 0; it < 16; ++it) {
    int idx = it * 256 + threadIdx.x;
    int r = idx >> 6, c = idx & 63;
    T[c * 65 + r] = src[(size_t)(s0 + r) * 3072 + c];
  }
  __syncthreads();
  #pragma unroll 4
  for (int it = 0; it < 16; ++it) {
    int idx = it * 256 + threadIdx.x;
    int d = idx >> 6, s = idx & 63;
    Vtg[((size_t)bk * 128 + d0 + d) * S + s0 + s] = T[d * 65 + s];
  }
}

// ---------------- causal flash attention, GQA 4:1, no-max softmax ----------------
// 2 waves x 64 q-rows. S^T via swapped MFMA operands -> P written as b64, read b128.
// LDS-staged K/V (xor-swizzled chunks), K/V fragments read once per wave per tile.
__global__ __launch_bounds__(128, 2) void attn_kernel(const u16* __restrict__ QKV,
                                                      const u16* __restrict__ Vtg,
                                                      u16* __restrict__ Ctx,
                                                      int B, int S)
{
  const int x = blockIdx.x;                 // 512 blocks
  const int t = x >> 5, bh = x & 31;
  const int qt = (x < 256) ? (15 - t) : (t - 8);   // heavy first; pairs (c,c+256) sum 15
  const int h = bh & 15, b = bh >> 4;
  const int tid  = threadIdx.x;
  const int wave = tid >> 6, lane = tid & 63;
  const int col  = lane & 15, quad = lane >> 4;
  const int q0   = qt * 128;
  const int kvh  = h >> 2;
  const int row0w = q0 + wave * 64;

  __shared__ u16 Ks[64 * 128];    // [key][d], 16B chunks phys = c ^ (key&15)
  __shared__ u16 Vt[128 * 64];    // [d][key], 16B chunks phys = c ^ (d&7)
  __shared__ u16 Ps[2][64 * 72];  // per-wave P: [qrow][key], stride 72

  // Q B-operand frags (scale log2e/sqrt(128) pre-folded in rope)
  bf16x8 aq[4][4];
  #pragma unroll
  for (int mt = 0; mt < 4; ++mt)
    #pragma unroll
    for (int ks = 0; ks < 4; ++ks)
      aq[mt][ks] = *(const bf16x8*)(QKV + (size_t)(b * S + row0w + mt * 16 + col) * 3072
                                        + h * 128 + ks * 32 + quad * 8);

  const u16* KVb = QKV + (size_t)b * S * 3072 + 2048 + kvh * 128;
  const u16* Vtb = Vtg + ((size_t)(b * 4 + kvh) * 128) * S;
  u16* Pw = Ps[wave];

  const f32x4 fz = {0.f, 0.f, 0.f, 0.f};
  f32x4 o[4][8];
  #pragma unroll
  for (int mt = 0; mt < 4; ++mt)
    #pragma unroll
    for (int nc = 0; nc < 8; ++nc) o[mt][nc] = fz;
  float rs[4] = {0.f, 0.f, 0.f, 0.f};   // per-lane: qrow = row0w + mt*16 + col

  const int kt_max = 2 * qt + 1;

  for (int kt = 0; kt <= kt_max; ++kt) {
    __syncthreads();   // prior tile reads done
    // stage K: 64 rows x 16 chunks; per wave 8 issues x 4 rows
    #pragma unroll
    for (int i = 0; i < 8; ++i) {
      int r = wave * 32 + i * 4 + (lane >> 4);
      int lc = (lane & 15) ^ (r & 15);
      gld16(KVb + (size_t)(kt * 64 + r) * 3072 + lc * 8, Ks + (wave * 32 + i * 4) * 128);
    }
    // stage V^T: 128 rows x 8 chunks; per wave 8 issues x 8 rows
    #pragma unroll
    for (int i = 0; i < 8; ++i) {
      int r = wave * 64 + i * 8 + (lane >> 3);
      int lc = (lane & 7) ^ (r & 7);
      gld16(Vtb + (size_t)r * S + kt * 64 + lc * 8, Vt + (wave * 64 + i * 8) * 64);
    }
    __syncthreads();   // drain -> staged data visible

    if (kt * 64 > row0w + 63) continue;   // wave fully masked (uniform; barriers above)
    const bool need_mask = (kt * 64 + 63 > row0w);

    // S^T = K Q^T per 16-key group; write P[qrow][key] as b64
    #pragma unroll
    for (int nt = 0; nt < 4; ++nt) {
      bf16x8 kA[4];
      #pragma unroll
      for (int ks = 0; ks < 4; ++ks)
        kA[ks] = *(const bf16x8*)&Ks[(nt * 16 + col) * 128 + (((ks * 4 + quad) ^ col) * 8)];
      #pragma unroll
      for (int mt = 0; mt < 4; ++mt) {
        f32x4 st = fz;
        #pragma unroll
        for (int ks = 0; ks < 4; ++ks)
          st = __builtin_amdgcn_mfma_f32_16x16x32_bf16(kA[ks], aq[mt][ks], st, 0, 0, 0);
        // lane: key = kt*64 + nt*16 + quad*4 + i, qrow = row0w + mt*16 + col
        float pv[4];
        const int kbase = kt * 64 + nt * 16 + quad * 4;
        const int qrow  = row0w + mt * 16 + col;
        #pragma unroll
        for (int i = 0; i < 4; ++i) {
          float s = st[i];
          if (need_mask && (kbase + i > qrow)) s = -__builtin_inff();
          pv[i] = exp2f(s);
        }
        rs[mt] += (pv[0] + pv[1]) + (pv[2] + pv[3]);
        uint32_t d0 = (__float_as_uint(pv[0]) >> 16) | (__float_as_uint(pv[1]) & 0xffff0000u);
        uint32_t d1 = (__float_as_uint(pv[2]) >> 16) | (__float_as_uint(pv[3]) & 0xffff0000u);
        uint2 dd; dd.x = d0; dd.y = d1;
        *(uint2*)&Pw[(mt * 16 + col) * 72 + nt * 16 + quad * 4] = dd;
      }
    }
    __asm__ volatile("" ::: "memory");

    // PV: P A-frags (b128 from Ps), V^T B-frags read once, reused across mt
    bf16x8 ap[4][2];
    #pragma unroll
    for (int mt = 0; mt < 4; ++mt)
      #pragma unroll
      for (int ks = 0; ks < 2; ++ks)
        ap[mt][ks] = *(const bf16x8*)&Pw[(mt * 16 + col) * 72 + ks * 32 + quad * 8];
    #pragma unroll
    for (int nc = 0; nc < 8; ++nc) {
      #pragma unroll
      for (int ks = 0; ks < 2; ++ks) {
        bf16x8 bv = *(const bf16x8*)&Vt[(nc * 16 + col) * 64 + (((ks * 4 + quad) ^ (col & 7)) * 8)];
        #pragma unroll
        for (int mt = 0; mt < 4; ++mt)
          o[mt][nc] = __builtin_amdgcn_mfma_f32_16x16x32_bf16(ap[mt][ks], bv, o[mt][nc], 0, 0, 0);
      }
    }
  }

  // epilogue: total row-sum = reduce rs over the 4 quad-copies of each col
  #pragma unroll
  for (int mt = 0; mt < 4; ++mt) {
    float v = rs[mt];
    v += __shfl_xor(v, 16);
    v += __shfl_xor(v, 32);
    float lv[4];
    #pragma unroll
    for (int i = 0; i < 4; ++i)
      lv[i] = 1.0f / __shfl(v, quad * 4 + i);   // lane (quad*4+i) holds qrow row0w+mt*16+quad*4+i
    #pragma unroll
    for (int nc = 0; nc < 8; ++nc)
      #pragma unroll
      for (int i = 0; i < 4; ++i) {
        int qg = row0w + mt * 16 + quad * 4 + i;
        Ctx[(size_t)(b * S + qg) * 2048 + h * 128 + nc * 16 + col] =
            f2bf(o[mt][nc][i] * lv[i]);
      }
  }
}

extern "C" void kernel_launch(void* const* d_in, const int* in_sizes, int n_in,
                              void* d_out, int out_size, void* d_ws, size_t ws_size,
                              hipStream_t stream) {
  const int B = 2, S = 2048, D = 2048;
  const int M = B * S;            // 4096
  const int NQKV = 3072;          // q 0..2047 | k 2048..2559 | v 2560..3071

  const float* x  = (const float*)d_in[0];
  const float* wq = (const float*)d_in[1];
  const float* wk = (const float*)d_in[2];
  const float* wv = (const float*)d_in[3];
  const float* wo = (const float*)d_in[4];

  char* ws = (char*)d_ws;
  u16* xb    = (u16*)ws; ws += (size_t)M * D * 2;
  u16* wqkvb = (u16*)ws; ws += (size_t)NQKV * D * 2;
  u16* wob   = (u16*)ws; ws += (size_t)D * D * 2;
  u16* qkvb  = (u16*)ws; ws += (size_t)M * NQKV * 2;
  u16* vtg   = (u16*)ws; ws += (size_t)B * 4 * 128 * S * 2;
  u16* ctx   = (u16*)ws; ws += (size_t)M * D * 2;

  cast_all<<<18432, 256, 0, stream>>>(x, wq, wk, wv, wo, xb, wqkvb, wob);

  gemm_bt<<<dim3(NQKV / 128, M / 128), 256, 0, stream>>>(xb, wqkvb, qkvb, M, NQKV, D, 0);

  // qscale = log2(e)/sqrt(128), folded so attention uses exp2 directly
  const float qscale = 0.12751744515623627f;
  rope_kernel<<<(M * 20 * 64) / 256, 256, 0, stream>>>(qkvb, S, qscale);

  vtrans_kernel<<<dim3(S / 64, 2, B * 4), 256, 0, stream>>>(qkvb, vtg, S);

  attn_kernel<<<512, 128, 0, stream>>>(qkvb, vtg, ctx, B, S);

  gemm_bt<<<dim3(D / 128, M / 128), 256, 0, stream>>>(ctx, wob, d_out, M, D, D, 1);
}

// Round 6
// 309.368 us; speedup vs baseline: 1.5968x; 1.4564x over previous
//
#include <hip/hip_runtime.h>
#include <stdint.h>

typedef unsigned short u16;
typedef __attribute__((ext_vector_type(8))) __bf16 bf16x8;
typedef __attribute__((ext_vector_type(4))) float f32x4;

__device__ __forceinline__ u16 f2bf(float f) {
  union { float f; uint32_t u; } v; v.f = f;
  uint32_t u = v.u;
  uint32_t r = (u + 0x7fffu + ((u >> 16) & 1u)) >> 16;  // RNE
  return (u16)r;
}
__device__ __forceinline__ float bf2f(u16 h) {
  union { uint32_t u; float f; } v; v.u = ((uint32_t)h) << 16;
  return v.f;
}

// async 16B/lane global->LDS. LDS dest = wave-uniform base + lane*16 (m104).
__device__ __forceinline__ void gld16(const void* g, void* l) {
  __builtin_amdgcn_global_load_lds(
      (__attribute__((address_space(1))) void*)(uintptr_t)g,
      (__attribute__((address_space(3))) void*)l,
      16, 0, 0);
}

// ---------------- fused fp32 -> bf16 cast of all 5 inputs ----------------
__global__ __launch_bounds__(256) void cast_all(const float* __restrict__ x,
                                                const float* __restrict__ wq,
                                                const float* __restrict__ wk,
                                                const float* __restrict__ wv,
                                                const float* __restrict__ wo,
                                                u16* __restrict__ xb,
                                                u16* __restrict__ wqkv,
                                                u16* __restrict__ wob) {
  int i = blockIdx.x * 256 + threadIdx.x;
  const float* src; u16* dst; int loc, base;
  if (i < 2097152)      { src = x;  dst = xb;   loc = i;           base = 0; }
  else if (i < 3145728) { src = wq; dst = wqkv; loc = i - 2097152; base = 0; }
  else if (i < 3407872) { src = wk; dst = wqkv; loc = i - 3145728; base = 1048576; }
  else if (i < 3670016) { src = wv; dst = wqkv; loc = i - 3407872; base = 1310720; }
  else                  { src = wo; dst = wob;  loc = i - 3670016; base = 0; }
  float4 f = ((const float4*)src)[loc];
  ushort4 o;
  o.x = f2bf(f.x); o.y = f2bf(f.y); o.z = f2bf(f.z); o.w = f2bf(f.w);
  ((ushort4*)dst)[base + loc] = o;
}

// ---------------- bf16 GEMM, C = A * B^T  (BK=64, m97-style staging) ----------------
__global__ __launch_bounds__(256) void gemm_bt(const u16* __restrict__ A,
                                               const u16* __restrict__ B,
                                               void* __restrict__ C,
                                               int M, int N, int K, int out_f32)
{
  __shared__ u16 As[128 * 64];
  __shared__ u16 Bs[128 * 64];
  const int tid  = threadIdx.x;
  const int wave = tid >> 6, lane = tid & 63;
  const int col  = lane & 15, quad = lane >> 4;
  const int bm = blockIdx.y, bn = blockIdx.x;
  const int wm = (wave >> 1) * 64, wn = (wave & 1) * 64;
  const size_t arow0 = (size_t)bm * 128, brow0 = (size_t)bn * 128;

  const int sr = lane >> 3, pc = lane & 7;

  const f32x4 fz = {0.f, 0.f, 0.f, 0.f};
  f32x4 acc[4][4];
  for (int i = 0; i < 4; ++i)
    for (int j = 0; j < 4; ++j) acc[i][j] = fz;

  for (int k0 = 0; k0 < K; k0 += 64) {
    __syncthreads();
    #pragma unroll
    for (int i = 0; i < 4; ++i) {
      int rA = wave * 32 + i * 8 + sr;
      int lc = pc ^ (rA & 7);
      gld16(A + (arow0 + rA) * K + k0 + lc * 8, As + (wave * 32 + i * 8) * 64);
      gld16(B + (brow0 + rA) * K + k0 + lc * 8, Bs + (wave * 32 + i * 8) * 64);
    }
    __syncthreads();
    #pragma unroll
    for (int kk = 0; kk < 2; ++kk) {
      const int swz = (((kk * 4 + quad) ^ (col & 7)) * 8);
      bf16x8 af[4];
      #pragma unroll
      for (int mt = 0; mt < 4; ++mt)
        af[mt] = *(const bf16x8*)&As[(wm + mt * 16 + col) * 64 + swz];
      #pragma unroll
      for (int nt = 0; nt < 4; ++nt) {
        bf16x8 bf = *(const bf16x8*)&Bs[(wn + nt * 16 + col) * 64 + swz];
        #pragma unroll
        for (int mt = 0; mt < 4; ++mt)
          acc[mt][nt] = __builtin_amdgcn_mfma_f32_16x16x32_bf16(af[mt], bf, acc[mt][nt], 0, 0, 0);
      }
    }
  }

  #pragma unroll
  for (int mt = 0; mt < 4; ++mt)
    #pragma unroll
    for (int nt = 0; nt < 4; ++nt)
      #pragma unroll
      for (int i = 0; i < 4; ++i) {
        size_t grow = arow0 + wm + mt * 16 + quad * 4 + i;
        size_t gcol = brow0 + wn + nt * 16 + col;
        float v = acc[mt][nt][i];
        if (out_f32) ((float*)C)[grow * N + gcol] = v;
        else         ((u16*)C)[grow * N + gcol]   = f2bf(v);
      }
}

// ---------------- RoPE over fused qkv buffer (row stride 3072) ----------------
__global__ __launch_bounds__(256) void rope_kernel(u16* __restrict__ t, int S, float qscale) {
  int idx = blockIdx.x * 256 + threadIdx.x;   // total = B*S*20*64
  int i = idx & 63;
  int r = idx >> 6;
  int hh = r % 20; r /= 20;
  int s = r % S;
  int b = r / S;
  float inv = exp2f(-(float)i * 0.20762050593046f);  // 10000^(-2i/128)
  float ang = (float)s * inv;
  float sn, cs;
  __sincosf(ang, &sn, &cs);
  int colb = (hh < 16) ? hh * 128 : 2048 + (hh - 16) * 128;
  float osc = (hh < 16) ? qscale : 1.0f;
  size_t base = (size_t)(b * S + s) * 3072 + colb + 2 * i;
  float t0 = bf2f(t[base]), t1 = bf2f(t[base + 1]);
  t[base]     = f2bf((t0 * cs - t1 * sn) * osc);
  t[base + 1] = f2bf((t0 * sn + t1 * cs) * osc);
}

// ---------------- V transpose: qkv[:,2560+kvh*128+d] -> Vtg[(b*4+kvh)*128+d][s] ----
__global__ __launch_bounds__(256) void vtrans_kernel(const u16* __restrict__ qkv,
                                                     u16* __restrict__ Vtg, int S) {
  __shared__ u16 T[64 * 65];
  const int s0 = blockIdx.x * 64, d0 = blockIdx.y * 64, bk = blockIdx.z;
  const int b = bk >> 2, kvh = bk & 3;
  const u16* src = qkv + (size_t)b * S * 3072 + 2560 + kvh * 128 + d0;
  #pragma unroll 4
  for (int it = 0; it < 16; ++it) {
    int idx = it * 256 + threadIdx.x;
    int r = idx >> 6, c = idx & 63;
    T[c * 65 + r] = src[(size_t)(s0 + r) * 3072 + c];
  }
  __syncthreads();
  #pragma unroll 4
  for (int it = 0; it < 16; ++it) {
    int idx = it * 256 + threadIdx.x;
    int d = idx >> 6, s = idx & 63;
    Vtg[((size_t)bk * 128 + d0 + d) * S + s0 + s] = T[d * 65 + s];
  }
}

// ---------------- causal flash attention, GQA 4:1, no-max softmax ----------------
// 4 waves x 32 q-rows (no spills). S^T via swapped MFMA operands -> P b64 writes.
// K/V LDS-staged; kA/bv fragments read once per wave, reused across mt.
__global__ __launch_bounds__(256, 2) void attn_kernel(const u16* __restrict__ QKV,
                                                      const u16* __restrict__ Vtg,
                                                      u16* __restrict__ Ctx,
                                                      int B, int S)
{
  const int x = blockIdx.x;                 // 512 blocks
  const int t = x >> 5, bh = x & 31;
  const int qt = (x < 256) ? (15 - t) : (t - 8);   // heavy first; pairs (c,c+256) sum 15
  const int h = bh & 15, b = bh >> 4;
  const int tid  = threadIdx.x;
  const int wave = tid >> 6, lane = tid & 63;
  const int col  = lane & 15, quad = lane >> 4;
  const int q0   = qt * 128;
  const int kvh  = h >> 2;
  const int row0w = q0 + wave * 32;

  __shared__ u16 Ks[64 * 128];    // [key][d], 16B chunks phys = c ^ (key&15)
  __shared__ u16 Vt[128 * 64];    // [d][key], 16B chunks phys = c ^ (d&7)
  __shared__ u16 Ps[4][32 * 72];  // per-wave P: [qrow][key], stride 72

  // Q B-operand frags (scale log2e/sqrt(128) pre-folded in rope)
  bf16x8 aq[2][4];
  #pragma unroll
  for (int mt = 0; mt < 2; ++mt)
    #pragma unroll
    for (int ks = 0; ks < 4; ++ks)
      aq[mt][ks] = *(const bf16x8*)(QKV + (size_t)(b * S + row0w + mt * 16 + col) * 3072
                                        + h * 128 + ks * 32 + quad * 8);

  const u16* KVb = QKV + (size_t)b * S * 3072 + 2048 + kvh * 128;
  const u16* Vtb = Vtg + ((size_t)(b * 4 + kvh) * 128) * S;
  u16* Pw = Ps[wave];

  const f32x4 fz = {0.f, 0.f, 0.f, 0.f};
  f32x4 o[2][8];
  #pragma unroll
  for (int mt = 0; mt < 2; ++mt)
    #pragma unroll
    for (int nc = 0; nc < 8; ++nc) o[mt][nc] = fz;
  float rs[2] = {0.f, 0.f};   // per-lane: qrow = row0w + mt*16 + col

  const int kt_max = 2 * qt + 1;

  for (int kt = 0; kt <= kt_max; ++kt) {
    __syncthreads();   // prior tile reads done
    // stage K: 64 rows x 16 chunks; per wave 4 issues x 4 rows
    #pragma unroll
    for (int i = 0; i < 4; ++i) {
      int r = wave * 16 + i * 4 + (lane >> 4);
      int lc = (lane & 15) ^ (r & 15);
      gld16(KVb + (size_t)(kt * 64 + r) * 3072 + lc * 8, Ks + (wave * 16 + i * 4) * 128);
    }
    // stage V^T: 128 rows x 8 chunks; per wave 4 issues x 8 rows
    #pragma unroll
    for (int i = 0; i < 4; ++i) {
      int r = wave * 32 + i * 8 + (lane >> 3);
      int lc = (lane & 7) ^ (r & 7);
      gld16(Vtb + (size_t)r * S + kt * 64 + lc * 8, Vt + (wave * 32 + i * 8) * 64);
    }
    __syncthreads();   // drain -> staged data visible

    if (kt * 64 > row0w + 31) continue;   // wave fully masked (uniform; barriers above)
    const bool need_mask = (kt * 64 + 63 > row0w);

    // S^T = K Q^T per 16-key group; write P[qrow][key] as b64
    #pragma unroll
    for (int nt = 0; nt < 4; ++nt) {
      bf16x8 kA[4];
      #pragma unroll
      for (int ks = 0; ks < 4; ++ks)
        kA[ks] = *(const bf16x8*)&Ks[(nt * 16 + col) * 128 + (((ks * 4 + quad) ^ col) * 8)];
      #pragma unroll
      for (int mt = 0; mt < 2; ++mt) {
        f32x4 st = fz;
        #pragma unroll
        for (int ks = 0; ks < 4; ++ks)
          st = __builtin_amdgcn_mfma_f32_16x16x32_bf16(kA[ks], aq[mt][ks], st, 0, 0, 0);
        // lane: key = kt*64 + nt*16 + quad*4 + i, qrow = row0w + mt*16 + col
        float pv[4];
        const int kbase = kt * 64 + nt * 16 + quad * 4;
        const int qrow  = row0w + mt * 16 + col;
        #pragma unroll
        for (int i = 0; i < 4; ++i) {
          float s = st[i];
          if (need_mask && (kbase + i > qrow)) s = -__builtin_inff();
          pv[i] = exp2f(s);
        }
        rs[mt] += (pv[0] + pv[1]) + (pv[2] + pv[3]);
        uint32_t d0 = (__float_as_uint(pv[0]) >> 16) | (__float_as_uint(pv[1]) & 0xffff0000u);
        uint32_t d1 = (__float_as_uint(pv[2]) >> 16) | (__float_as_uint(pv[3]) & 0xffff0000u);
        uint2 dd; dd.x = d0; dd.y = d1;
        *(uint2*)&Pw[(mt * 16 + col) * 72 + nt * 16 + quad * 4] = dd;
      }
    }
    __asm__ volatile("" ::: "memory");

    // PV: P A-frags (b128), V^T B-frags read once, reused across mt
    bf16x8 ap[2][2];
    #pragma unroll
    for (int mt = 0; mt < 2; ++mt)
      #pragma unroll
      for (int ks = 0; ks < 2; ++ks)
        ap[mt][ks] = *(const bf16x8*)&Pw[(mt * 16 + col) * 72 + ks * 32 + quad * 8];
    #pragma unroll
    for (int nc = 0; nc < 8; ++nc) {
      #pragma unroll
      for (int ks = 0; ks < 2; ++ks) {
        bf16x8 bv = *(const bf16x8*)&Vt[(nc * 16 + col) * 64 + (((ks * 4 + quad) ^ (col & 7)) * 8)];
        #pragma unroll
        for (int mt = 0; mt < 2; ++mt)
          o[mt][nc] = __builtin_amdgcn_mfma_f32_16x16x32_bf16(ap[mt][ks], bv, o[mt][nc], 0, 0, 0);
      }
    }
  }

  // epilogue: reduce rs over the 4 quad-copies, normalize, store
  #pragma unroll
  for (int mt = 0; mt < 2; ++mt) {
    float v = rs[mt];
    v += __shfl_xor(v, 16);
    v += __shfl_xor(v, 32);
    float lv[4];
    #pragma unroll
    for (int i = 0; i < 4; ++i)
      lv[i] = 1.0f / __shfl(v, quad * 4 + i);
    #pragma unroll
    for (int nc = 0; nc < 8; ++nc)
      #pragma unroll
      for (int i = 0; i < 4; ++i) {
        int qg = row0w + mt * 16 + quad * 4 + i;
        Ctx[(size_t)(b * S + qg) * 2048 + h * 128 + nc * 16 + col] =
            f2bf(o[mt][nc][i] * lv[i]);
      }
  }
}

extern "C" void kernel_launch(void* const* d_in, const int* in_sizes, int n_in,
                              void* d_out, int out_size, void* d_ws, size_t ws_size,
                              hipStream_t stream) {
  const int B = 2, S = 2048, D = 2048;
  const int M = B * S;            // 4096
  const int NQKV = 3072;          // q 0..2047 | k 2048..2559 | v 2560..3071

  const float* x  = (const float*)d_in[0];
  const float* wq = (const float*)d_in[1];
  const float* wk = (const float*)d_in[2];
  const float* wv = (const float*)d_in[3];
  const float* wo = (const float*)d_in[4];

  char* ws = (char*)d_ws;
  u16* xb    = (u16*)ws; ws += (size_t)M * D * 2;
  u16* wqkvb = (u16*)ws; ws += (size_t)NQKV * D * 2;
  u16* wob   = (u16*)ws; ws += (size_t)D * D * 2;
  u16* qkvb  = (u16*)ws; ws += (size_t)M * NQKV * 2;
  u16* vtg   = (u16*)ws; ws += (size_t)B * 4 * 128 * S * 2;
  u16* ctx   = (u16*)ws; ws += (size_t)M * D * 2;

  cast_all<<<18432, 256, 0, stream>>>(x, wq, wk, wv, wo, xb, wqkvb, wob);

  gemm_bt<<<dim3(NQKV / 128, M / 128), 256, 0, stream>>>(xb, wqkvb, qkvb, M, NQKV, D, 0);

  // qscale = log2(e)/sqrt(128), folded so attention uses exp2 directly
  const float qscale = 0.12751744515623627f;
  rope_kernel<<<(M * 20 * 64) / 256, 256, 0, stream>>>(qkvb, S, qscale);

  vtrans_kernel<<<dim3(S / 64, 2, B * 4), 256, 0, stream>>>(qkvb, vtg, S);

  attn_kernel<<<512, 256, 0, stream>>>(qkvb, vtg, ctx, B, S);

  gemm_bt<<<dim3(D / 128, M / 128), 256, 0, stream>>>(ctx, wob, d_out, M, D, D, 1);
}